// Round 1
// baseline (428.113 us; speedup 1.0000x reference)
//
#include <hip/hip_runtime.h>
#include <math.h>

// SSIM loss, fused single-pass.
// Input: img1, img2 fp32 [32,1,1024,1024]. Output: scalar fp32 = 1 - mean(ssim_map).
// Separable 11x11 Gaussian conv (sigma=1.5) of 5 fields {a,b,a2,b2,ab}:
//  - horizontal pass in registers from an LDS-staged input row (double-buffered)
//  - vertical pass via an 11-slot register accumulator ring (static mod-11 via unroll)
// Tile: 256 cols (1 col/thread) x 64 rows per block. Grid 4x16x32 = 2048 blocks.

#define IMG_W 1024
#define IMG_H 1024
#define NIMG  32
#define TW    256
#define TH    64
#define HALO  5
#define KW    11
#define STEPS 77   // 7*11 ; rows needed = TH+10 = 74, padded to multiple of 11

#define C1f (0.01f * 0.01f)
#define C2f (0.03f * 0.03f)

struct GW { float w[KW]; };

__global__ __launch_bounds__(256, 4)
void ssim_main(const float* __restrict__ img1, const float* __restrict__ img2,
               double* __restrict__ acc_out, GW gw)
{
    __shared__ float sb1[2][TW + 16];
    __shared__ float sb2[2][TW + 16];
    __shared__ float wsum[4];

    const int tid = threadIdx.x;
    const int c0 = blockIdx.x * TW;   // output col base
    const int r0 = blockIdx.y * TH;   // output row base
    const size_t imgoff = (size_t)blockIdx.z * (IMG_W * IMG_H);
    const float* p1 = img1 + imgoff;
    const float* p2 = img2 + imgoff;

    float w[KW];
#pragma unroll
    for (int i = 0; i < KW; ++i) w[i] = gw.w[i];

    // acc[slot][field]; fields: 0=a 1=b 2=aa 3=bb 4=ab
    float acc[KW][5];
#pragma unroll
    for (int j = 0; j < KW; ++j)
#pragma unroll
        for (int f = 0; f < 5; ++f) acc[j][f] = 0.0f;

    float lsum = 0.0f;

    // Stage one padded input row (cols c0-5 .. c0+TW+4) of both images into LDS buffer `buf`.
    auto load_row = [&](int s, int buf) {
        const int gr = r0 + s - HALO;
        const bool rok = ((unsigned)gr < (unsigned)IMG_H);
        const float* row1 = p1 + (size_t)gr * IMG_W;
        const float* row2 = p2 + (size_t)gr * IMG_W;
#pragma unroll
        for (int e0 = 0; e0 < TW + 2 * HALO; e0 += 256) {
            int e = e0 + tid;
            if (e < TW + 2 * HALO) {
                int gc = c0 - HALO + e;
                bool ok = rok && ((unsigned)gc < (unsigned)IMG_W);
                sb1[buf][e] = ok ? row1[gc] : 0.0f;
                sb2[buf][e] = ok ? row2[gc] : 0.0f;
            }
        }
    };

    load_row(0, 0);

    for (int so = 0; so < STEPS / KW; ++so) {
#pragma unroll
        for (int u = 0; u < KW; ++u) {
            const int s = so * KW + u;
            __syncthreads();
            // prefetch next row into the other buffer (reads of it finished before the sync)
            if (s + 1 < STEPS) load_row(s + 1, (s + 1) & 1);

            // horizontal 11-tap conv of the 5 fields, registers only
            const float* b1 = sb1[s & 1];
            const float* b2 = sb2[s & 1];
            float hv0 = 0.f, hv1 = 0.f, hv2 = 0.f, hv3 = 0.f, hv4 = 0.f;
#pragma unroll
            for (int i = 0; i < KW; ++i) {
                float a = b1[tid + i];
                float b = b2[tid + i];
                float wi = w[i];
                hv0 += wi * a;
                hv1 += wi * b;
                hv2 += wi * (a * a);
                hv3 += wi * (b * b);
                hv4 += wi * (a * b);
            }

            // vertical accumulate into ring; slot j==u starts fresh (k=0 -> overwrite)
#pragma unroll
            for (int j = 0; j < KW; ++j) {
                const int k = (u - j + KW) % KW;  // compile-time after unroll
                const float wk = w[k];
                if (k == 0) {
                    acc[j][0] = wk * hv0; acc[j][1] = wk * hv1; acc[j][2] = wk * hv2;
                    acc[j][3] = wk * hv3; acc[j][4] = wk * hv4;
                } else {
                    acc[j][0] += wk * hv0; acc[j][1] += wk * hv1; acc[j][2] += wk * hv2;
                    acc[j][3] += wk * hv3; acc[j][4] += wk * hv4;
                }
            }

            // output row r = s-10 completed in slot (u+1)%11
            if (s >= 10 && s <= TH + 9) {
                const int je = (u + 1) % KW;
                float mu1 = acc[je][0], mu2 = acc[je][1];
                float caa = acc[je][2], cbb = acc[je][3], cab = acc[je][4];
                float mu1s = mu1 * mu1, mu2s = mu2 * mu2, mu12 = mu1 * mu2;
                float sg1 = caa - mu1s, sg2 = cbb - mu2s, sg12 = cab - mu12;
                float num = (2.0f * mu12 + C1f) * (2.0f * sg12 + C2f);
                float den = (mu1s + mu2s + C1f) * (sg1 + sg2 + C2f);
                lsum += num / den;
            }
        }
    }

    // block reduction: wave shuffle then LDS across the 4 waves
    float v = lsum;
#pragma unroll
    for (int off = 32; off > 0; off >>= 1) v += __shfl_down(v, off);
    __syncthreads();
    if ((tid & 63) == 0) wsum[tid >> 6] = v;
    __syncthreads();
    if (tid == 0) {
        float bsum = wsum[0] + wsum[1] + wsum[2] + wsum[3];
        atomicAdd(acc_out, (double)bsum);
    }
}

__global__ void ssim_finalize(const double* __restrict__ acc, float* __restrict__ out)
{
    out[0] = 1.0f - (float)(acc[0] * (1.0 / ((double)NIMG * IMG_W * IMG_H)));
}

extern "C" void kernel_launch(void* const* d_in, const int* in_sizes, int n_in,
                              void* d_out, int out_size, void* d_ws, size_t ws_size,
                              hipStream_t stream)
{
    const float* img1 = (const float*)d_in[0];
    const float* img2 = (const float*)d_in[1];
    float* out = (float*)d_out;
    double* accbuf = (double*)d_ws;

    // Gaussian weights exactly as the reference: exp in f64, cast f32, normalize
    GW gw;
    {
        float g[KW];
        double s = 0.0;
        for (int i = 0; i < KW; ++i) {
            int x = i - KW / 2;
            g[i] = (float)exp(-(double)(x * x) / (2.0 * 1.5 * 1.5));
            s += (double)g[i];
        }
        for (int i = 0; i < KW; ++i) gw.w[i] = (float)((double)g[i] / s);
    }

    hipMemsetAsync(accbuf, 0, sizeof(double), stream);
    dim3 grid(IMG_W / TW, IMG_H / TH, NIMG);
    ssim_main<<<grid, 256, 0, stream>>>(img1, img2, accbuf, gw);
    ssim_finalize<<<1, 1, 0, stream>>>(accbuf, out);
}